// Round 1
// 474.543 us; speedup vs baseline: 1.0172x; 1.0172x over previous
//
#include <hip/hip_runtime.h>
#include <stdint.h>

// ---------- helpers ----------
typedef __attribute__((ext_vector_type(8))) short bf16x8;
typedef __attribute__((ext_vector_type(4))) float f32x4;

__device__ __forceinline__ float bf16lo_to_f(uint32_t u) { return __uint_as_float(u << 16); }
__device__ __forceinline__ float bf16hi_to_f(uint32_t u) { return __uint_as_float(u & 0xffff0000u); }
__device__ __forceinline__ uint16_t f_to_bf16(float f) {
    uint32_t u = __float_as_uint(f);
    uint32_t r = u + 0x7fff + ((u >> 16) & 1);   // round-to-nearest-even
    return (uint16_t)(r >> 16);
}

// Layouts:
//  Txg : bf16 [5][N+1][128] -- slot-major Chebyshev state; row = 256B; row N = 0 sentinel
//  ew  : uint2 [E + 8N]     -- {col<<8 (byte offset into slot), w as f32 bits}; padded w=0
//  Weights constant across all 8 lhat passes (no quant scales anymore).

#define BINCH 4096

__global__ void __launch_bounds__(256) k_bhist(const int* __restrict__ row,
                                               int* __restrict__ bhist, int E) {
    __shared__ int sh[256];
    int t = threadIdx.x;
    sh[t] = 0;
    __syncthreads();
    int stride = gridDim.x * blockDim.x;
    for (int e = blockIdx.x * blockDim.x + t; e < E; e += stride)
        atomicAdd(&sh[row[e] >> 8], 1);
    __syncthreads();
    if (sh[t]) atomicAdd(&bhist[t], sh[t]);
}

// scan bucket counts -> gbase/gcur
__global__ void k_bscan(const int* __restrict__ bhist, int* __restrict__ gbase,
                        int* __restrict__ gcur, int nbk) {
    __shared__ int sh[256];
    int t = threadIdx.x;
    int v = t < nbk ? bhist[t] : 0;
    sh[t] = v;
    __syncthreads();
    for (int o = 1; o < 256; o <<= 1) {
        int u = (t >= o) ? sh[t - o] : 0;
        __syncthreads();
        sh[t] += u;
        __syncthreads();
    }
    gbase[t] = sh[t] - v;
    gcur[t] = sh[t] - v;
    if (t == 255) gbase[256] = sh[255];
}

// bin edges into bucket-sorted list; entry = (row&255) | (col<<8)
__global__ void __launch_bounds__(256) k_bin(const int* __restrict__ row,
        const int* __restrict__ col, int* __restrict__ gcur,
        uint32_t* __restrict__ bout, int E) {
    __shared__ uint32_t stage[BINCH];
    __shared__ int hist[256], hscan[256], hcur[256], gofs[256];
    int t = threadIdx.x;
    int e0 = blockIdx.x * BINCH;
    int ecnt = min(BINCH, E - e0);
    hist[t] = 0;
    __syncthreads();
    for (int i = t; i < ecnt; i += 256)
        atomicAdd(&hist[row[e0 + i] >> 8], 1);
    __syncthreads();
    int v = hist[t];
    hscan[t] = v;
    __syncthreads();
    for (int o = 1; o < 256; o <<= 1) {
        int u = (t >= o) ? hscan[t - o] : 0;
        __syncthreads();
        hscan[t] += u;
        __syncthreads();
    }
    hcur[t] = hscan[t] - v;
    __syncthreads();
    for (int i = t; i < ecnt; i += 256) {
        int r = row[e0 + i];
        int p = atomicAdd(&hcur[r >> 8], 1);
        stage[p] = (uint32_t)(r & 255) | ((uint32_t)col[e0 + i] << 8);
    }
    __syncthreads();
    if (v > 0) gofs[t] = atomicAdd(&gcur[t], v);
    __syncthreads();
    for (int i = t; i < ecnt; i += 256) {
        int lo = 0, hi = 255;
        while (lo < hi) { int mid = (lo + hi) >> 1; if (hscan[mid] > i) hi = mid; else lo = mid + 1; }
        int b = lo;
        int local = i - (hscan[b] - hist[b]);
        bout[gofs[b] + local] = stage[i];
    }
}

// per-node degree from bucket lists, fused with padded per-block sum (psum)
__global__ void __launch_bounds__(256) k_deg2(const uint32_t* __restrict__ bout,
        const int* __restrict__ gbase, int* __restrict__ deg,
        int* __restrict__ psum, int N) {
    __shared__ int cnt[256];
    __shared__ int red[256];
    int t = threadIdx.x, b = blockIdx.x;
    cnt[t] = 0;
    __syncthreads();
    int s = gbase[b], epos = gbase[b + 1];
    for (int i = s + t; i < epos; i += 256)
        atomicAdd(&cnt[bout[i] & 255], 1);
    __syncthreads();
    int n = b * 256 + t;
    int d = cnt[t];
    if (n < N) deg[n] = d;
    red[t] = (n < N) ? ((d + 7) & ~7) : 0;
    __syncthreads();
    for (int o = 128; o > 0; o >>= 1) {
        if (t < o) red[t] += red[t + o];
        __syncthreads();
    }
    if (t == 0) psum[b] = red[0];
}

// offs (self-computed block prefix over psum) + dis/diag
__global__ void k_offs(const int* __restrict__ deg, const int* __restrict__ psum,
                       int* __restrict__ offs,
                       const int* __restrict__ batch, const float* __restrict__ lam,
                       float* __restrict__ dis, float* __restrict__ diag,
                       int N, int nb) {
    __shared__ int pre[256];
    __shared__ int sh[256];
    int t = threadIdx.x, b = blockIdx.x;
    pre[t] = (t < b) ? psum[t] : 0;
    __syncthreads();
    for (int o = 128; o > 0; o >>= 1) {
        if (t < o) pre[t] += pre[t + o];
        __syncthreads();
    }
    int base = pre[0];
    __syncthreads();
    int idx = b * 256 + t;
    int d = idx < N ? deg[idx] : 0;
    int v = (d + 7) & ~7;
    sh[t] = v;
    __syncthreads();
    for (int o = 1; o < 256; o <<= 1) {
        int u = (t >= o) ? sh[t - o] : 0;
        __syncthreads();
        sh[t] += u;
        __syncthreads();
    }
    if (idx < N) {
        offs[idx] = base + sh[t] - v;
        dis[idx] = d > 0 ? rsqrtf((float)d) : 0.f;
        diag[idx] = 2.f / lam[batch[idx]] - 1.f;
    }
    if (b == nb - 1 && t == 255) offs[N] = base + sh[255];
}

// final scatter: build {col<<8, w} edge array (bucket-local) + zero-weight padding
__global__ void __launch_bounds__(256) k_ew(const uint32_t* __restrict__ bout,
        const int* __restrict__ gbase, const int* __restrict__ offs,
        const float* __restrict__ dis, const float* __restrict__ diag,
        uint2* __restrict__ ew, int N) {
    __shared__ int cur[256];
    __shared__ float srw[256];        // per-local-row  -dis[r]*(diag[r]+1) = -2*dis[r]/lam
    int t = threadIdx.x, b = blockIdx.x;
    int n = b * 256 + t;
    int o0 = n < N ? offs[n] : 0;
    cur[t] = o0;
    srw[t] = (n < N) ? (-dis[n] * (diag[n] + 1.0f)) : 0.f;
    __syncthreads();
    int s = gbase[b], epos = gbase[b + 1];
    for (int i = s + t; i < epos; i += 256) {
        uint32_t v = bout[i];
        int r = (int)(v & 255u);
        int c = (int)(v >> 8);
        int p = atomicAdd(&cur[r], 1);
        float w = srw[r] * dis[c];    // full edge weight, constant across all passes
        ew[p] = make_uint2((uint32_t)c << 8, __float_as_uint(w));
    }
    __syncthreads();
    if (n < N) {
        int e = cur[t];
        int pe = o0 + ((e - o0 + 7) & ~7);
        uint2 pad = make_uint2((uint32_t)N << 8, 0u);   // sentinel row N is zeroed
        for (int p = e; p < pe; p++) ew[p] = pad;
    }
}

// W1,W2 [5][128][128] fp32 -> Wt bf16 [128 out][640 kk]; fused pair
__global__ void k_prepw(const float* __restrict__ W1, uint16_t* __restrict__ Wt1,
                        const float* __restrict__ W2, uint16_t* __restrict__ Wt2) {
    int i = blockIdx.x * blockDim.x + threadIdx.x;
    const float* W = W1; uint16_t* Wt = Wt1;
    if (i >= 128 * 640) { i -= 128 * 640; W = W2; Wt = Wt2; }
    int o = i / 640, kk = i % 640;
    Wt[(size_t)o * 640 + kk] = f_to_bf16(W[(size_t)kk * 128 + o]);
}

// x fp32 [N][128] -> Txg slot 0 bf16; wave n==N zeroes the 5 sentinel rows
__global__ void __launch_bounds__(256) k_castx(const float* __restrict__ x,
        uint16_t* __restrict__ Txg, int N) {
    int n = (blockIdx.x * blockDim.x + threadIdx.x) >> 6;
    int lane = threadIdx.x & 63;
    if (n > N) return;
    size_t ss32 = (size_t)(N + 1) * 64;          // u32 per slot
    if (n == N) {
#pragma unroll
        for (int s = 0; s < 5; s++)
            ((uint32_t*)Txg)[s * ss32 + (size_t)N * 64 + lane] = 0u;
        return;
    }
    float2 v = ((const float2*)x)[(size_t)n * 64 + lane];
    uint32_t p = (uint32_t)f_to_bf16(v.x) | ((uint32_t)f_to_bf16(v.y) << 16);
    ((uint32_t*)Txg)[(size_t)n * 64 + lane] = p;
}

// dst = alpha*(sum_e w_e*src[col] + diag*src[n]) - (use_prev ? prev : 0)   [pure bf16]
__global__ void __launch_bounds__(256) k_lhat(uint16_t* Txg,
        const int* __restrict__ offs, const uint2* __restrict__ ew,
        const float* __restrict__ diag, int N,
        int src, int dst, int prev, float alpha, int use_prev) {
    int n = (blockIdx.x * blockDim.x + threadIdx.x) >> 6;
    int lane = threadIdx.x & 63;
    if (n >= N) return;
    int beg = offs[n], end = offs[n + 1];        // padded: multiple of 8
    size_t sb = (size_t)(N + 1) * 256;           // bytes per slot
    const uint8_t* srcs = (const uint8_t*)Txg + (size_t)src * sb;
    uint32_t lo4 = (uint32_t)lane * 4;
    float ax = 0.f, ay = 0.f;
    for (int e = beg; e < end; e += 8) {
        const uint4* ep = (const uint4*)(ew + e);
        uint4 a = ep[0], b4 = ep[1], c4 = ep[2], d4 = ep[3];
        uint32_t co[8]; float wv[8];
        co[0] = a.x;  wv[0] = __uint_as_float(a.y);
        co[1] = a.z;  wv[1] = __uint_as_float(a.w);
        co[2] = b4.x; wv[2] = __uint_as_float(b4.y);
        co[3] = b4.z; wv[3] = __uint_as_float(b4.w);
        co[4] = c4.x; wv[4] = __uint_as_float(c4.y);
        co[5] = c4.z; wv[5] = __uint_as_float(c4.w);
        co[6] = d4.x; wv[6] = __uint_as_float(d4.y);
        co[7] = d4.z; wv[7] = __uint_as_float(d4.w);
        uint32_t q[8];
#pragma unroll
        for (int u = 0; u < 8; u++)
            q[u] = *(const uint32_t*)(srcs + (co[u] + lo4));
#pragma unroll
        for (int u = 0; u < 8; u++) {
            ax = fmaf(wv[u], bf16lo_to_f(q[u]), ax);
            ay = fmaf(wv[u], bf16hi_to_f(q[u]), ay);
        }
    }
    float dgn = diag[n];
    uint32_t roff = ((uint32_t)n << 8) + lo4;
    uint32_t qs = *(const uint32_t*)(srcs + roff);
    ax = fmaf(dgn, bf16lo_to_f(qs), ax);
    ay = fmaf(dgn, bf16hi_to_f(qs), ay);
    float fx = alpha * ax, fy = alpha * ay;
    if (use_prev) {
        const uint8_t* prs = (const uint8_t*)Txg + (size_t)prev * sb;
        uint32_t qp = *(const uint32_t*)(prs + roff);
        fx -= bf16lo_to_f(qp);
        fy -= bf16hi_to_f(qp);
    }
    uint32_t outv = (uint32_t)f_to_bf16(fx) | ((uint32_t)f_to_bf16(fy) << 16);
    *(uint32_t*)((uint8_t*)Txg + (size_t)dst * sb + roff) = outv;
}

// ---------- GEMM: relu(A[M,640] @ Wt^T + bias), bf16 MFMA, BM=128 tile ----------
#define BM 128
#define BK 64
#define LDT 72
#define LDC 132

__global__ void __launch_bounds__(256) k_gemm(
        const uint16_t* __restrict__ A, size_t sstride,   // slot-major A; u16 per slot
        const uint16_t* __restrict__ Bt,
        const float* __restrict__ bias,
        uint16_t* __restrict__ out2b,              // bf16 slot0 (stride 128) or null
        float* __restrict__ pooled,                // fused pool accum or null
        const int* __restrict__ batch,
        int M, int Kdim) {
    __shared__ uint16_t smem[BM * LDT + 128 * LDT];
    uint16_t* As = smem;
    uint16_t* Bs = smem + BM * LDT;
    uint16_t* Ct = smem;
    int t = threadIdx.x;
    int w = t >> 6, lane = t & 63;
    int row0 = blockIdx.x * BM;
    int mrow = (w >> 1) * 64, ncol = (w & 1) * 64;

    int ar[4], akc[4];
#pragma unroll
    for (int rep = 0; rep < 4; rep++) {
        int d = rep * 256 + t;
        ar[rep] = d >> 3; akc[rep] = d & 7;
    }

    f32x4 acc[4][4];
#pragma unroll
    for (int i = 0; i < 4; i++)
#pragma unroll
        for (int j = 0; j < 4; j++) acc[i][j] = (f32x4){0.f, 0.f, 0.f, 0.f};

    bf16x8 pa[4], pb[4];
#pragma unroll
    for (int rep = 0; rep < 4; rep++) {
        int grow = row0 + ar[rep];
        int kk = akc[rep] * 8;
        bf16x8 va = {0, 0, 0, 0, 0, 0, 0, 0};
        if (grow < M)
            va = *(const bf16x8*)(A + (size_t)(kk >> 7) * sstride + (size_t)grow * 128 + (kk & 127));
        pa[rep] = va;
        pb[rep] = *(const bf16x8*)(Bt + (size_t)ar[rep] * Kdim + kk);
    }

    for (int k0 = 0; k0 < Kdim; k0 += BK) {
#pragma unroll
        for (int rep = 0; rep < 4; rep++) {
            *(bf16x8*)(&As[ar[rep] * LDT + akc[rep] * 8]) = pa[rep];
            *(bf16x8*)(&Bs[ar[rep] * LDT + akc[rep] * 8]) = pb[rep];
        }
        __syncthreads();
        int kn = k0 + BK;
        if (kn < Kdim) {
#pragma unroll
            for (int rep = 0; rep < 4; rep++) {
                int grow = row0 + ar[rep];
                int kk = kn + akc[rep] * 8;
                bf16x8 va = {0, 0, 0, 0, 0, 0, 0, 0};
                if (grow < M)
                    va = *(const bf16x8*)(A + (size_t)(kk >> 7) * sstride + (size_t)grow * 128 + (kk & 127));
                pa[rep] = va;
                pb[rep] = *(const bf16x8*)(Bt + (size_t)ar[rep] * Kdim + kk);
            }
        }
#pragma unroll
        for (int ks = 0; ks < BK; ks += 32) {
            bf16x8 af[4], bfr[4];
#pragma unroll
            for (int i = 0; i < 4; i++) {
                int r = mrow + i * 16 + (lane & 15);
                af[i] = *(const bf16x8*)(&As[r * LDT + ks + (lane >> 4) * 8]);
            }
#pragma unroll
            for (int j = 0; j < 4; j++) {
                int c = ncol + j * 16 + (lane & 15);
                bfr[j] = *(const bf16x8*)(&Bs[c * LDT + ks + (lane >> 4) * 8]);
            }
#pragma unroll
            for (int i = 0; i < 4; i++)
#pragma unroll
                for (int j = 0; j < 4; j++)
                    acc[i][j] = __builtin_amdgcn_mfma_f32_16x16x32_bf16(af[i], bfr[j], acc[i][j], 0, 0, 0);
        }
        __syncthreads();
    }

    // bias + relu -> bf16 into LDS
#pragma unroll
    for (int j = 0; j < 4; j++) {
        int c = ncol + j * 16 + (lane & 15);
        float bv = bias[c];
#pragma unroll
        for (int i = 0; i < 4; i++) {
            int rloc = mrow + i * 16 + (lane >> 4) * 4;
#pragma unroll
            for (int r = 0; r < 4; r++) {
                float v = acc[i][j][r] + bv;
                v = v > 0.f ? v : 0.f;
                Ct[(rloc + r) * LDC + c] = f_to_bf16(v);
            }
        }
    }
    __syncthreads();

    if (out2b) {
#pragma unroll
        for (int rep = 0; rep < 8; rep++) {
            int d = rep * 256 + t;
            int r = d >> 4, c8 = (d & 15) * 8;
            int grow = row0 + r;
            if (grow < M) {
                bf16x8 v = *(const bf16x8*)(&Ct[r * LDC + c8]);
                *(bf16x8*)(out2b + (size_t)grow * 128 + c8) = v;
            }
        }
    }
    if (pooled) {
        // fused mean-pool accumulation: thread t covers feature f = t&127,
        // rows [ (t>>7)*64, +64 ); batch sorted -> segmented flush
        int f = t & 127, r0 = (t >> 7) * 64;
        float accp = 0.f;
        int curb = -1;
        for (int r = r0; r < r0 + 64; ++r) {
            int grow = row0 + r;
            if (grow >= M) break;
            int b = batch[grow];
            if (b != curb) {
                if (curb >= 0) atomicAdd(&pooled[curb * 128 + f], accp);
                accp = 0.f; curb = b;
            }
            accp += __uint_as_float(((uint32_t)Ct[r * LDC + f]) << 16);
        }
        if (curb >= 0) atomicAdd(&pooled[curb * 128 + f], accp);
    }
}

// ---------- final linear (counts via binary search on sorted batch) ----------
__global__ void k_final(const float* __restrict__ pooled, const int* __restrict__ batch,
                        const float* __restrict__ Wlin, const float* __restrict__ blin,
                        float* __restrict__ out, int N, int B_, int C_) {
    __shared__ int cnt[64];
    int t = threadIdx.x;
    if (t < B_) {
        auto lb = [&](int v) {
            int lo = 0, hi = N;
            while (lo < hi) {
                int mid = (lo + hi) >> 1;
                if (batch[mid] < v) lo = mid + 1; else hi = mid;
            }
            return lo;
        };
        cnt[t] = lb(t + 1) - lb(t);
    }
    __syncthreads();
    if (t < B_ * C_) {
        int b = t / C_, c = t % C_;
        float inv = 1.f / fmaxf((float)cnt[b], 1.f);
        float acc = blin[c];
        for (int f = 0; f < 128; ++f) acc += pooled[b * 128 + f] * inv * Wlin[f * C_ + c];
        out[t] = acc;
    }
}

// ---------- launch ----------
extern "C" void kernel_launch(void* const* d_in, const int* in_sizes, int n_in,
                              void* d_out, int out_size, void* d_ws, size_t ws_size,
                              hipStream_t stream) {
    const float* x    = (const float*)d_in[0];
    const int*   edge = (const int*)d_in[1];
    const int*   batch= (const int*)d_in[2];
    const float* lam  = (const float*)d_in[3];
    const float* W1   = (const float*)d_in[4];
    const float* b1   = (const float*)d_in[5];
    const float* W2   = (const float*)d_in[6];
    const float* b2   = (const float*)d_in[7];
    const float* Wlin = (const float*)d_in[8];
    const float* blin = (const float*)d_in[9];
    const int E  = in_sizes[1] / 2;
    const int N  = in_sizes[2];
    const int B_ = in_sizes[3];
    const int* row = edge;
    const int* col = edge + E;

    char* ws = (char*)d_ws;
    size_t off = 0;
    auto take = [&](size_t bytes) -> char* {
        char* p = ws + off;
        off = (off + bytes + 255) & ~(size_t)255;
        return p;
    };
    uint16_t* Txg    = (uint16_t*)take((size_t)5 * (N + 1) * 128 * 2);
    uint2*    ew     = (uint2*)take(((size_t)E + 8 * (size_t)N) * 8);
    uint32_t* bout   = (uint32_t*)take((size_t)E * 4);
    int*      deg    = (int*)take((size_t)N * 4);
    int*      offs   = (int*)take((size_t)(N + 1) * 4);
    float*    dis    = (float*)take((size_t)N * 4);
    float*    diag   = (float*)take((size_t)N * 4);
    uint16_t* Wt1    = (uint16_t*)take((size_t)128 * 640 * 2);
    uint16_t* Wt2    = (uint16_t*)take((size_t)128 * 640 * 2);
    float*    pooled = (float*)take((size_t)B_ * 128 * 4);   // 256-aligned size
    int*      bhist  = (int*)take(257 * 4);                  // contiguous after pooled
    int*      gbase  = (int*)take(257 * 4);
    int*      gcur   = (int*)take(257 * 4);
    const int nb = (N + 255) / 256;
    int*      psum   = (int*)take((size_t)nb * 4);

    // one fill covers pooled (B_*512 bytes, 256-multiple) + bhist
    hipMemsetAsync(pooled, 0, (size_t)B_ * 128 * 4 + 257 * 4, stream);

    k_bhist<<<112, 256, 0, stream>>>(row, bhist, E);
    k_bscan<<<1, 256, 0, stream>>>(bhist, gbase, gcur, nb);
    k_bin<<<(E + BINCH - 1) / BINCH, 256, 0, stream>>>(row, col, gcur, bout, E);
    k_deg2<<<nb, 256, 0, stream>>>(bout, gbase, deg, psum, N);
    k_offs<<<nb, 256, 0, stream>>>(deg, psum, offs, batch, lam, dis, diag, N, nb);
    k_ew<<<nb, 256, 0, stream>>>(bout, gbase, offs, dis, diag, ew, N);
    k_prepw<<<(2 * 128 * 640) / 256, 256, 0, stream>>>(W1, Wt1, W2, Wt2);
    k_castx<<<(N + 4) / 4, 256, 0, stream>>>(x, Txg, N);   // covers node N (sentinels)

    const int lblocks = (N + 3) / 4;
    const int gblocks = (N + BM - 1) / BM;
    const size_t ss = (size_t)(N + 1) * 128;               // u16 per slot

    // layer 1
    k_lhat<<<lblocks, 256, 0, stream>>>(Txg, offs, ew, diag, N, 0, 1, 0, 1.f, 0);
    k_lhat<<<lblocks, 256, 0, stream>>>(Txg, offs, ew, diag, N, 1, 2, 0, 2.f, 1);
    k_lhat<<<lblocks, 256, 0, stream>>>(Txg, offs, ew, diag, N, 2, 3, 1, 2.f, 1);
    k_lhat<<<lblocks, 256, 0, stream>>>(Txg, offs, ew, diag, N, 3, 4, 2, 2.f, 1);
    k_gemm<<<gblocks, 256, 0, stream>>>(Txg, ss, Wt1, b1,
                                        Txg /* slot 0 */, (float*)nullptr, batch, N, 640);

    // layer 2
    k_lhat<<<lblocks, 256, 0, stream>>>(Txg, offs, ew, diag, N, 0, 1, 0, 1.f, 0);
    k_lhat<<<lblocks, 256, 0, stream>>>(Txg, offs, ew, diag, N, 1, 2, 0, 2.f, 1);
    k_lhat<<<lblocks, 256, 0, stream>>>(Txg, offs, ew, diag, N, 2, 3, 1, 2.f, 1);
    k_lhat<<<lblocks, 256, 0, stream>>>(Txg, offs, ew, diag, N, 3, 4, 2, 2.f, 1);
    k_gemm<<<gblocks, 256, 0, stream>>>(Txg, ss, Wt2, b2,
                                        (uint16_t*)nullptr, pooled, batch, N, 640);

    k_final<<<1, 128, 0, stream>>>(pooled, batch, Wlin, blin, (float*)d_out, N, B_, 10);
}

// Round 2
// 469.308 us; speedup vs baseline: 1.0285x; 1.0112x over previous
//
#include <hip/hip_runtime.h>
#include <stdint.h>

// ---------- helpers ----------
typedef __attribute__((ext_vector_type(8))) short bf16x8;
typedef __attribute__((ext_vector_type(4))) float f32x4;

__device__ __forceinline__ float bf16lo_to_f(uint32_t u) { return __uint_as_float(u << 16); }
__device__ __forceinline__ float bf16hi_to_f(uint32_t u) { return __uint_as_float(u & 0xffff0000u); }
__device__ __forceinline__ uint16_t f_to_bf16(float f) {
    uint32_t u = __float_as_uint(f);
    uint32_t r = u + 0x7fff + ((u >> 16) & 1);   // round-to-nearest-even
    return (uint16_t)(r >> 16);
}

// Layouts:
//  Txb : bf16 [5][N+1][128] -- GEMM A operand mirror (slot-major, 256B rows)
//  Txq : int8 [5][N+1][128] -- gather state (slot-major, 128B rows = 1 cache line)
//  mS  : f32  [5][N+1]      -- per-row quant scale; sentinel row N = 0
//  ew  : uint2 [E + 8N]     -- {col*128 (byte offset into int8 slot), w f32}; pad w=0
//        consumed 2-edges-per-wave-step: lanes<32 take even entry, lanes>=32 odd.

#define BINCH 4096

__global__ void __launch_bounds__(256) k_bhist(const int* __restrict__ row,
                                               int* __restrict__ bhist, int E) {
    __shared__ int sh[256];
    int t = threadIdx.x;
    sh[t] = 0;
    __syncthreads();
    int stride = gridDim.x * blockDim.x;
    for (int e = blockIdx.x * blockDim.x + t; e < E; e += stride)
        atomicAdd(&sh[row[e] >> 8], 1);
    __syncthreads();
    if (sh[t]) atomicAdd(&bhist[t], sh[t]);
}

// scan bucket counts -> gbase/gcur; also zero mS sentinel rows
__global__ void k_bscan(const int* __restrict__ bhist, int* __restrict__ gbase,
                        int* __restrict__ gcur, float* __restrict__ mS, int nbk, int N) {
    __shared__ int sh[256];
    int t = threadIdx.x;
    int v = t < nbk ? bhist[t] : 0;
    sh[t] = v;
    __syncthreads();
    for (int o = 1; o < 256; o <<= 1) {
        int u = (t >= o) ? sh[t - o] : 0;
        __syncthreads();
        sh[t] += u;
        __syncthreads();
    }
    gbase[t] = sh[t] - v;
    gcur[t] = sh[t] - v;
    if (t == 255) gbase[256] = sh[255];
    if (t < 5) mS[(size_t)t * (N + 1) + N] = 0.f;
}

// bin edges into bucket-sorted list; entry = (row&255) | (col<<8)
__global__ void __launch_bounds__(256) k_bin(const int* __restrict__ row,
        const int* __restrict__ col, int* __restrict__ gcur,
        uint32_t* __restrict__ bout, int E) {
    __shared__ uint32_t stage[BINCH];
    __shared__ int hist[256], hscan[256], hcur[256], gofs[256];
    int t = threadIdx.x;
    int e0 = blockIdx.x * BINCH;
    int ecnt = min(BINCH, E - e0);
    hist[t] = 0;
    __syncthreads();
    for (int i = t; i < ecnt; i += 256)
        atomicAdd(&hist[row[e0 + i] >> 8], 1);
    __syncthreads();
    int v = hist[t];
    hscan[t] = v;
    __syncthreads();
    for (int o = 1; o < 256; o <<= 1) {
        int u = (t >= o) ? hscan[t - o] : 0;
        __syncthreads();
        hscan[t] += u;
        __syncthreads();
    }
    hcur[t] = hscan[t] - v;
    __syncthreads();
    for (int i = t; i < ecnt; i += 256) {
        int r = row[e0 + i];
        int p = atomicAdd(&hcur[r >> 8], 1);
        stage[p] = (uint32_t)(r & 255) | ((uint32_t)col[e0 + i] << 8);
    }
    __syncthreads();
    if (v > 0) gofs[t] = atomicAdd(&gcur[t], v);
    __syncthreads();
    for (int i = t; i < ecnt; i += 256) {
        int lo = 0, hi = 255;
        while (lo < hi) { int mid = (lo + hi) >> 1; if (hscan[mid] > i) hi = mid; else lo = mid + 1; }
        int b = lo;
        int local = i - (hscan[b] - hist[b]);
        bout[gofs[b] + local] = stage[i];
    }
}

// per-node degree from bucket lists, fused with padded per-block sum (psum)
__global__ void __launch_bounds__(256) k_deg2(const uint32_t* __restrict__ bout,
        const int* __restrict__ gbase, int* __restrict__ deg,
        int* __restrict__ psum, int N) {
    __shared__ int cnt[256];
    __shared__ int red[256];
    int t = threadIdx.x, b = blockIdx.x;
    cnt[t] = 0;
    __syncthreads();
    int s = gbase[b], epos = gbase[b + 1];
    for (int i = s + t; i < epos; i += 256)
        atomicAdd(&cnt[bout[i] & 255], 1);
    __syncthreads();
    int n = b * 256 + t;
    int d = cnt[t];
    if (n < N) deg[n] = d;
    red[t] = (n < N) ? ((d + 7) & ~7) : 0;
    __syncthreads();
    for (int o = 128; o > 0; o >>= 1) {
        if (t < o) red[t] += red[t + o];
        __syncthreads();
    }
    if (t == 0) psum[b] = red[0];
}

// offs (self-computed block prefix over psum) + dis/diag
__global__ void k_offs(const int* __restrict__ deg, const int* __restrict__ psum,
                       int* __restrict__ offs,
                       const int* __restrict__ batch, const float* __restrict__ lam,
                       float* __restrict__ dis, float* __restrict__ diag,
                       int N, int nb) {
    __shared__ int pre[256];
    __shared__ int sh[256];
    int t = threadIdx.x, b = blockIdx.x;
    pre[t] = (t < b) ? psum[t] : 0;
    __syncthreads();
    for (int o = 128; o > 0; o >>= 1) {
        if (t < o) pre[t] += pre[t + o];
        __syncthreads();
    }
    int base = pre[0];
    __syncthreads();
    int idx = b * 256 + t;
    int d = idx < N ? deg[idx] : 0;
    int v = (d + 7) & ~7;
    sh[t] = v;
    __syncthreads();
    for (int o = 1; o < 256; o <<= 1) {
        int u = (t >= o) ? sh[t - o] : 0;
        __syncthreads();
        sh[t] += u;
        __syncthreads();
    }
    if (idx < N) {
        offs[idx] = base + sh[t] - v;
        dis[idx] = d > 0 ? rsqrtf((float)d) : 0.f;
        diag[idx] = 2.f / lam[batch[idx]] - 1.f;
    }
    if (b == nb - 1 && t == 255) offs[N] = base + sh[255];
}

// final scatter: build {col*128, w} edge array (bucket-local) + zero-weight padding
__global__ void __launch_bounds__(256) k_ew(const uint32_t* __restrict__ bout,
        const int* __restrict__ gbase, const int* __restrict__ offs,
        const float* __restrict__ dis, const float* __restrict__ diag,
        uint2* __restrict__ ew, int N) {
    __shared__ int cur[256];
    __shared__ float srw[256];        // per-local-row  -dis[r]*(diag[r]+1) = -2*dis[r]/lam
    int t = threadIdx.x, b = blockIdx.x;
    int n = b * 256 + t;
    int o0 = n < N ? offs[n] : 0;
    cur[t] = o0;
    srw[t] = (n < N) ? (-dis[n] * (diag[n] + 1.0f)) : 0.f;
    __syncthreads();
    int s = gbase[b], epos = gbase[b + 1];
    for (int i = s + t; i < epos; i += 256) {
        uint32_t v = bout[i];
        int r = (int)(v & 255u);
        int c = (int)(v >> 8);
        int p = atomicAdd(&cur[r], 1);
        float w = srw[r] * dis[c];    // full edge weight, constant across all passes
        ew[p] = make_uint2((uint32_t)c << 7, __float_as_uint(w));   // int8 row = 128B
    }
    __syncthreads();
    if (n < N) {
        int e = cur[t];
        int pe = o0 + ((e - o0 + 7) & ~7);
        uint2 pad = make_uint2((uint32_t)N << 7, 0u);   // w=0 -> contribution 0
        for (int p = e; p < pe; p++) ew[p] = pad;
    }
}

// W1,W2 [5][128][128] fp32 -> Wt bf16 [128 out][640 kk]; fused pair
__global__ void k_prepw(const float* __restrict__ W1, uint16_t* __restrict__ Wt1,
                        const float* __restrict__ W2, uint16_t* __restrict__ Wt2) {
    int i = blockIdx.x * blockDim.x + threadIdx.x;
    const float* W = W1; uint16_t* Wt = Wt1;
    if (i >= 128 * 640) { i -= 128 * 640; W = W2; Wt = Wt2; }
    int o = i / 640, kk = i % 640;
    Wt[(size_t)o * 640 + kk] = f_to_bf16(W[(size_t)kk * 128 + o]);
}

// x fp32 [N][128] -> slot 0: bf16 row + int8 row + scale
__global__ void __launch_bounds__(256) k_castx(const float* __restrict__ x,
        uint16_t* __restrict__ Txb, int8_t* __restrict__ Txq,
        float* __restrict__ mS, int N) {
    int n = (blockIdx.x * blockDim.x + threadIdx.x) >> 6;
    int lane = threadIdx.x & 63;
    if (n >= N) return;
    float2 v = ((const float2*)x)[(size_t)n * 64 + lane];
    uint32_t p = (uint32_t)f_to_bf16(v.x) | ((uint32_t)f_to_bf16(v.y) << 16);
    ((uint32_t*)Txb)[(size_t)n * 64 + lane] = p;
    float m = fmaxf(fabsf(v.x), fabsf(v.y));
    for (int o = 1; o < 64; o <<= 1) m = fmaxf(m, __shfl_xor(m, o));
    float inv = m > 0.f ? 127.f / m : 0.f;
    int qx = (int)rintf(v.x * inv), qy = (int)rintf(v.y * inv);
    *(uint16_t*)(Txq + (size_t)n * 128 + 2 * lane) = (uint16_t)((qx & 0xff) | ((qy & 0xff) << 8));
    if (lane == 0) mS[n] = m > 0.f ? m * (1.f / 127.f) : 0.f;
}

// dst = alpha*(sum_e w_e*src[col] + diag*src[n]) - (use_prev ? prev : 0)
// int8 gather state (1 line/edge), 2 edges per wave-step (32 lanes each),
// software-pipelined edge-descriptor prefetch. Writes bf16 mirror + int8 + scale.
__global__ void __launch_bounds__(256) k_lhat(
        int8_t* __restrict__ Txq, uint16_t* __restrict__ Txb,
        float* __restrict__ mS,
        const int* __restrict__ offs, const uint2* __restrict__ ew,
        const float* __restrict__ diag, int N,
        int src, int dst, int prev, float alpha, int use_prev) {
    int n = (blockIdx.x * blockDim.x + threadIdx.x) >> 6;
    int lane = threadIdx.x & 63;
    if (n >= N) return;
    int beg = offs[n], end = offs[n + 1];          // padded: multiple of 8
    int h = lane >> 5, g = lane & 31;
    size_t sq = (size_t)(N + 1) * 128;             // int8 slot bytes
    const int8_t* srcq = Txq + (size_t)src * sq;
    const float* msrc = mS + (size_t)src * (N + 1);
    uint32_t lo4 = (uint32_t)g * 4;
    const uint2* ewh = ew + h;                     // my half's entry for step p: ewh[e + 2p]
    float a0 = 0.f, a1 = 0.f, a2 = 0.f, a3 = 0.f;
    if (beg < end) {
        uint2 ep[4];
#pragma unroll
        for (int p = 0; p < 4; p++) ep[p] = ewh[beg + 2 * p];
        int e = beg;
        while (true) {
            uint32_t q[4]; float mm[4], wv[4];
#pragma unroll
            for (int p = 0; p < 4; p++) {
                uint32_t co = ep[p].x;
                wv[p] = __uint_as_float(ep[p].y);
                q[p] = *(const uint32_t*)(srcq + co + lo4);
                mm[p] = *(const float*)((const char*)msrc + (co >> 5));   // col*4
            }
            int e2 = e + 8;
            bool more = e2 < end;
            uint2 epn[4];
            if (more) {
#pragma unroll
                for (int p = 0; p < 4; p++) epn[p] = ewh[e2 + 2 * p];
            }
#pragma unroll
            for (int p = 0; p < 4; p++) {
                float f = wv[p] * mm[p];
                a0 = fmaf(f, (float)(int)(int8_t)(q[p] & 0xff), a0);
                a1 = fmaf(f, (float)(int)(int8_t)((q[p] >> 8) & 0xff), a1);
                a2 = fmaf(f, (float)(int)(int8_t)((q[p] >> 16) & 0xff), a2);
                a3 = fmaf(f, (float)(int)(int8_t)(q[p] >> 24), a3);
            }
            if (!more) break;
            e = e2;
#pragma unroll
            for (int p = 0; p < 4; p++) ep[p] = epn[p];
        }
    }
    // combine the two edge-halves (each lane then holds features g*4..g*4+3)
    a0 += __shfl_xor(a0, 32);
    a1 += __shfl_xor(a1, 32);
    a2 += __shfl_xor(a2, 32);
    a3 += __shfl_xor(a3, 32);
    // self diagonal term
    uint32_t rq = (uint32_t)n * 128 + lo4;
    uint32_t qs = *(const uint32_t*)(srcq + rq);
    float ssc = msrc[n] * diag[n];
    a0 = fmaf(ssc, (float)(int)(int8_t)(qs & 0xff), a0);
    a1 = fmaf(ssc, (float)(int)(int8_t)((qs >> 8) & 0xff), a1);
    a2 = fmaf(ssc, (float)(int)(int8_t)((qs >> 16) & 0xff), a2);
    a3 = fmaf(ssc, (float)(int)(int8_t)(qs >> 24), a3);
    float f0 = alpha * a0, f1 = alpha * a1, f2 = alpha * a2, f3 = alpha * a3;
    if (use_prev) {
        uint32_t qp = *(const uint32_t*)(Txq + (size_t)prev * sq + rq);
        float sp = mS[(size_t)prev * (N + 1) + n];
        f0 = fmaf(-sp, (float)(int)(int8_t)(qp & 0xff), f0);
        f1 = fmaf(-sp, (float)(int)(int8_t)((qp >> 8) & 0xff), f1);
        f2 = fmaf(-sp, (float)(int)(int8_t)((qp >> 16) & 0xff), f2);
        f3 = fmaf(-sp, (float)(int)(int8_t)(qp >> 24), f3);
    }
    // bf16 mirror write (lanes of half 0 only; 32 lanes x 8B = 256B row)
    if (h == 0) {
        uint2 pk;
        pk.x = (uint32_t)f_to_bf16(f0) | ((uint32_t)f_to_bf16(f1) << 16);
        pk.y = (uint32_t)f_to_bf16(f2) | ((uint32_t)f_to_bf16(f3) << 16);
        *(uint2*)(Txb + (size_t)dst * (size_t)(N + 1) * 128 + (size_t)n * 128 + g * 4) = pk;
    }
    // requant (halves hold identical values -> 5 xor rounds suffice)
    float m = fmaxf(fmaxf(fabsf(f0), fabsf(f1)), fmaxf(fabsf(f2), fabsf(f3)));
#pragma unroll
    for (int o = 1; o < 32; o <<= 1) m = fmaxf(m, __shfl_xor(m, o));
    float inv = m > 0.f ? 127.f / m : 0.f;
    if (h == 0) {
        int q0 = (int)rintf(f0 * inv), q1 = (int)rintf(f1 * inv);
        int q2 = (int)rintf(f2 * inv), q3 = (int)rintf(f3 * inv);
        uint32_t pkq = (uint32_t)(q0 & 0xff) | ((uint32_t)(q1 & 0xff) << 8) |
                       ((uint32_t)(q2 & 0xff) << 16) | ((uint32_t)(q3 & 0xff) << 24);
        *(uint32_t*)(Txq + (size_t)dst * sq + rq) = pkq;
    }
    if (lane == 0) mS[(size_t)dst * (N + 1) + n] = m * (1.f / 127.f);
}

// ---------- GEMM: relu(A[M,640] @ Wt^T + bias), bf16 MFMA, BM=128 tile ----------
#define BM 128
#define BK 64
#define LDT 72
#define LDC 132

__global__ void __launch_bounds__(256) k_gemm(
        const uint16_t* __restrict__ A, size_t sstride,   // slot-major A; u16 per slot
        const uint16_t* __restrict__ Bt,
        const float* __restrict__ bias,
        uint16_t* __restrict__ out2b,              // bf16 slot0 (stride 128) or null
        int8_t* __restrict__ out2q,                // int8 slot0 (stride 128) or null
        float* __restrict__ msOut,                 // mS slot0 base (scales) or null
        float* __restrict__ pooled,                // fused pool accum or null
        const int* __restrict__ batch,
        int M, int Kdim) {
    __shared__ uint16_t smem[BM * LDT + 128 * LDT];
    uint16_t* As = smem;
    uint16_t* Bs = smem + BM * LDT;
    uint16_t* Ct = smem;
    int t = threadIdx.x;
    int w = t >> 6, lane = t & 63;
    int row0 = blockIdx.x * BM;
    int mrow = (w >> 1) * 64, ncol = (w & 1) * 64;

    int ar[4], akc[4];
#pragma unroll
    for (int rep = 0; rep < 4; rep++) {
        int d = rep * 256 + t;
        ar[rep] = d >> 3; akc[rep] = d & 7;
    }

    f32x4 acc[4][4];
#pragma unroll
    for (int i = 0; i < 4; i++)
#pragma unroll
        for (int j = 0; j < 4; j++) acc[i][j] = (f32x4){0.f, 0.f, 0.f, 0.f};

    bf16x8 pa[4], pb[4];
#pragma unroll
    for (int rep = 0; rep < 4; rep++) {
        int grow = row0 + ar[rep];
        int kk = akc[rep] * 8;
        bf16x8 va = {0, 0, 0, 0, 0, 0, 0, 0};
        if (grow < M)
            va = *(const bf16x8*)(A + (size_t)(kk >> 7) * sstride + (size_t)grow * 128 + (kk & 127));
        pa[rep] = va;
        pb[rep] = *(const bf16x8*)(Bt + (size_t)ar[rep] * Kdim + kk);
    }

    for (int k0 = 0; k0 < Kdim; k0 += BK) {
#pragma unroll
        for (int rep = 0; rep < 4; rep++) {
            *(bf16x8*)(&As[ar[rep] * LDT + akc[rep] * 8]) = pa[rep];
            *(bf16x8*)(&Bs[ar[rep] * LDT + akc[rep] * 8]) = pb[rep];
        }
        __syncthreads();
        int kn = k0 + BK;
        if (kn < Kdim) {
#pragma unroll
            for (int rep = 0; rep < 4; rep++) {
                int grow = row0 + ar[rep];
                int kk = kn + akc[rep] * 8;
                bf16x8 va = {0, 0, 0, 0, 0, 0, 0, 0};
                if (grow < M)
                    va = *(const bf16x8*)(A + (size_t)(kk >> 7) * sstride + (size_t)grow * 128 + (kk & 127));
                pa[rep] = va;
                pb[rep] = *(const bf16x8*)(Bt + (size_t)ar[rep] * Kdim + kk);
            }
        }
#pragma unroll
        for (int ks = 0; ks < BK; ks += 32) {
            bf16x8 af[4], bfr[4];
#pragma unroll
            for (int i = 0; i < 4; i++) {
                int r = mrow + i * 16 + (lane & 15);
                af[i] = *(const bf16x8*)(&As[r * LDT + ks + (lane >> 4) * 8]);
            }
#pragma unroll
            for (int j = 0; j < 4; j++) {
                int c = ncol + j * 16 + (lane & 15);
                bfr[j] = *(const bf16x8*)(&Bs[c * LDT + ks + (lane >> 4) * 8]);
            }
#pragma unroll
            for (int i = 0; i < 4; i++)
#pragma unroll
                for (int j = 0; j < 4; j++)
                    acc[i][j] = __builtin_amdgcn_mfma_f32_16x16x32_bf16(af[i], bfr[j], acc[i][j], 0, 0, 0);
        }
        __syncthreads();
    }

    // bias + relu -> bf16 into LDS
#pragma unroll
    for (int j = 0; j < 4; j++) {
        int c = ncol + j * 16 + (lane & 15);
        float bv = bias[c];
#pragma unroll
        for (int i = 0; i < 4; i++) {
            int rloc = mrow + i * 16 + (lane >> 4) * 4;
#pragma unroll
            for (int r = 0; r < 4; r++) {
                float v = acc[i][j][r] + bv;
                v = v > 0.f ? v : 0.f;
                Ct[(rloc + r) * LDC + c] = f_to_bf16(v);
            }
        }
    }
    __syncthreads();

    if (out2b) {
#pragma unroll
        for (int rep = 0; rep < 8; rep++) {
            int d = rep * 256 + t;
            int r = d >> 4, c8 = (d & 15) * 8;
            int grow = row0 + r;
            if (grow < M) {
                bf16x8 v = *(const bf16x8*)(&Ct[r * LDC + c8]);
                *(bf16x8*)(out2b + (size_t)grow * 128 + c8) = v;
            }
        }
    }
    if (out2q) {
        int r = t >> 1, half = t & 1;
        int grow = row0 + r;
        float vmax = 0.f;
        for (int j = 0; j < 32; j++) {
            uint32_t u = *(const uint32_t*)(&Ct[r * LDC + half * 64 + j * 2]);
            vmax = fmaxf(vmax, fmaxf(fabsf(bf16lo_to_f(u)), fabsf(bf16hi_to_f(u))));
        }
        vmax = fmaxf(vmax, __shfl_xor(vmax, 1));
        if (grow < M) {
            float inv = vmax > 0.f ? 127.f / vmax : 0.f;
            for (int j0 = 0; j0 < 16; j0++) {
                uint32_t u0 = *(const uint32_t*)(&Ct[r * LDC + half * 64 + j0 * 4]);
                uint32_t u1 = *(const uint32_t*)(&Ct[r * LDC + half * 64 + j0 * 4 + 2]);
                int q0 = (int)rintf(bf16lo_to_f(u0) * inv);
                int q1 = (int)rintf(bf16hi_to_f(u0) * inv);
                int q2 = (int)rintf(bf16lo_to_f(u1) * inv);
                int q3 = (int)rintf(bf16hi_to_f(u1) * inv);
                uint32_t pk = (uint32_t)(q0 & 0xff) | ((uint32_t)(q1 & 0xff) << 8) |
                              ((uint32_t)(q2 & 0xff) << 16) | ((uint32_t)(q3 & 0xff) << 24);
                *(uint32_t*)(out2q + (size_t)grow * 128 + half * 64 + j0 * 4) = pk;
            }
            if (half == 0) msOut[grow] = vmax * (1.f / 127.f);
        }
    }
    if (pooled) {
        // fused mean-pool accumulation: thread t covers feature f = t&127,
        // rows [ (t>>7)*64, +64 ); batch sorted -> segmented flush
        int f = t & 127, r0 = (t >> 7) * 64;
        float accp = 0.f;
        int curb = -1;
        for (int r = r0; r < r0 + 64; ++r) {
            int grow = row0 + r;
            if (grow >= M) break;
            int b = batch[grow];
            if (b != curb) {
                if (curb >= 0) atomicAdd(&pooled[curb * 128 + f], accp);
                accp = 0.f; curb = b;
            }
            accp += __uint_as_float(((uint32_t)Ct[r * LDC + f]) << 16);
        }
        if (curb >= 0) atomicAdd(&pooled[curb * 128 + f], accp);
    }
}

// ---------- final linear (counts via binary search on sorted batch) ----------
__global__ void k_final(const float* __restrict__ pooled, const int* __restrict__ batch,
                        const float* __restrict__ Wlin, const float* __restrict__ blin,
                        float* __restrict__ out, int N, int B_, int C_) {
    __shared__ int cnt[64];
    int t = threadIdx.x;
    if (t < B_) {
        auto lb = [&](int v) {
            int lo = 0, hi = N;
            while (lo < hi) {
                int mid = (lo + hi) >> 1;
                if (batch[mid] < v) lo = mid + 1; else hi = mid;
            }
            return lo;
        };
        cnt[t] = lb(t + 1) - lb(t);
    }
    __syncthreads();
    if (t < B_ * C_) {
        int b = t / C_, c = t % C_;
        float inv = 1.f / fmaxf((float)cnt[b], 1.f);
        float acc = blin[c];
        for (int f = 0; f < 128; ++f) acc += pooled[b * 128 + f] * inv * Wlin[f * C_ + c];
        out[t] = acc;
    }
}

// ---------- launch ----------
extern "C" void kernel_launch(void* const* d_in, const int* in_sizes, int n_in,
                              void* d_out, int out_size, void* d_ws, size_t ws_size,
                              hipStream_t stream) {
    const float* x    = (const float*)d_in[0];
    const int*   edge = (const int*)d_in[1];
    const int*   batch= (const int*)d_in[2];
    const float* lam  = (const float*)d_in[3];
    const float* W1   = (const float*)d_in[4];
    const float* b1   = (const float*)d_in[5];
    const float* W2   = (const float*)d_in[6];
    const float* b2   = (const float*)d_in[7];
    const float* Wlin = (const float*)d_in[8];
    const float* blin = (const float*)d_in[9];
    const int E  = in_sizes[1] / 2;
    const int N  = in_sizes[2];
    const int B_ = in_sizes[3];
    const int* row = edge;
    const int* col = edge + E;

    char* ws = (char*)d_ws;
    size_t off = 0;
    auto take = [&](size_t bytes) -> char* {
        char* p = ws + off;
        off = (off + bytes + 255) & ~(size_t)255;
        return p;
    };
    uint16_t* Txb    = (uint16_t*)take((size_t)5 * (N + 1) * 128 * 2);   // 64MB
    int8_t*   Txq    = (int8_t*)take((size_t)5 * (N + 1) * 128);         // 32MB
    uint2*    ew     = (uint2*)take(((size_t)E + 8 * (size_t)N) * 8);
    float*    mS     = (float*)take((size_t)5 * (N + 1) * 4);
    int*      deg    = (int*)take((size_t)N * 4);
    int*      offs   = (int*)take((size_t)(N + 1) * 4);
    float*    dis    = (float*)take((size_t)N * 4);
    float*    diag   = (float*)take((size_t)N * 4);
    uint16_t* Wt1    = (uint16_t*)take((size_t)128 * 640 * 2);
    uint16_t* Wt2    = (uint16_t*)take((size_t)128 * 640 * 2);
    float*    pooled = (float*)take((size_t)B_ * 128 * 4);   // 256-aligned size
    int*      bhist  = (int*)take(257 * 4);                  // contiguous after pooled
    int*      gbase  = (int*)take(257 * 4);
    int*      gcur   = (int*)take(257 * 4);
    const int nb = (N + 255) / 256;
    int*      psum   = (int*)take((size_t)nb * 4);
    // bout aliased into Txb slot-4 region (12.8MB >= E*4B; slot 4 is only
    // written by the 4th lhat pass, long after bout's last read in k_ew)
    uint32_t* bout   = (uint32_t*)((char*)Txb + (size_t)4 * (N + 1) * 256);

    // one fill covers pooled (B_*512 bytes, 256-multiple) + bhist
    hipMemsetAsync(pooled, 0, (size_t)B_ * 128 * 4 + 257 * 4, stream);

    k_bhist<<<112, 256, 0, stream>>>(row, bhist, E);
    k_bscan<<<1, 256, 0, stream>>>(bhist, gbase, gcur, mS, nb, N);
    k_bin<<<(E + BINCH - 1) / BINCH, 256, 0, stream>>>(row, col, gcur, bout, E);
    k_deg2<<<nb, 256, 0, stream>>>(bout, gbase, deg, psum, N);
    k_offs<<<nb, 256, 0, stream>>>(deg, psum, offs, batch, lam, dis, diag, N, nb);
    k_ew<<<nb, 256, 0, stream>>>(bout, gbase, offs, dis, diag, ew, N);
    k_prepw<<<(2 * 128 * 640) / 256, 256, 0, stream>>>(W1, Wt1, W2, Wt2);
    k_castx<<<(N + 3) / 4, 256, 0, stream>>>(x, Txb, Txq, mS, N);

    const int lblocks = (N + 3) / 4;
    const int gblocks = (N + BM - 1) / BM;
    const size_t ss = (size_t)(N + 1) * 128;               // u16 per bf16 slot

    // layer 1
    k_lhat<<<lblocks, 256, 0, stream>>>(Txq, Txb, mS, offs, ew, diag, N, 0, 1, 0, 1.f, 0);
    k_lhat<<<lblocks, 256, 0, stream>>>(Txq, Txb, mS, offs, ew, diag, N, 1, 2, 0, 2.f, 1);
    k_lhat<<<lblocks, 256, 0, stream>>>(Txq, Txb, mS, offs, ew, diag, N, 2, 3, 1, 2.f, 1);
    k_lhat<<<lblocks, 256, 0, stream>>>(Txq, Txb, mS, offs, ew, diag, N, 3, 4, 2, 2.f, 1);
    k_gemm<<<gblocks, 256, 0, stream>>>(Txb, ss, Wt1, b1,
                                        Txb /* slot 0 */, Txq /* slot 0 */, mS /* slot 0 */,
                                        (float*)nullptr, batch, N, 640);

    // layer 2
    k_lhat<<<lblocks, 256, 0, stream>>>(Txq, Txb, mS, offs, ew, diag, N, 0, 1, 0, 1.f, 0);
    k_lhat<<<lblocks, 256, 0, stream>>>(Txq, Txb, mS, offs, ew, diag, N, 1, 2, 0, 2.f, 1);
    k_lhat<<<lblocks, 256, 0, stream>>>(Txq, Txb, mS, offs, ew, diag, N, 2, 3, 1, 2.f, 1);
    k_lhat<<<lblocks, 256, 0, stream>>>(Txq, Txb, mS, offs, ew, diag, N, 3, 4, 2, 2.f, 1);
    k_gemm<<<gblocks, 256, 0, stream>>>(Txb, ss, Wt2, b2,
                                        (uint16_t*)nullptr, (int8_t*)nullptr, (float*)nullptr,
                                        pooled, batch, N, 640);

    k_final<<<1, 128, 0, stream>>>(pooled, batch, Wlin, blin, (float*)d_out, N, B_, 10);
}